// Round 1
// baseline (1660.507 us; speedup 1.0000x reference)
//
#include <hip/hip_runtime.h>

// GCN 2-layer + linear head for MI355X.
// Pipeline:
//   deg -> dis=rsqrt(deg)
//   bufA = x@W1
//   bufB = 0; scatter-add edges (dis[src]*dis[dst]*bufA[src] -> bufB[dst])
//   bufB = relu(bufB + dis^2*bufA + b1)        (self-loop folded in epilogue)
//   bufA = bufB@W2
//   bufB = 0; scatter-add edges again
//   bufB = relu(bufB + dis^2*bufA + b2)
//   out  = bufB . Wl + bl

#define HID 64
#define INC 11

__global__ void k_init_deg(float* __restrict__ deg, int N) {
    int i = blockIdx.x * blockDim.x + threadIdx.x;
    if (i < N) deg[i] = 1.0f;   // self-loop
}

__global__ void k_count_deg(const int* __restrict__ col, int E, float* __restrict__ deg) {
    int i = blockIdx.x * blockDim.x + threadIdx.x;
    int stride = gridDim.x * blockDim.x;
    for (; i < E; i += stride) atomicAdd(&deg[col[i]], 1.0f);
}

__global__ void k_dis(float* __restrict__ deg, int N) {
    int i = blockIdx.x * blockDim.x + threadIdx.x;
    if (i < N) deg[i] = rsqrtf(deg[i]);   // deg >= 1 always
}

// h[N,64] = x[N,11] @ W1[11,64]
__global__ void k_xw1(const float* __restrict__ x, const float* __restrict__ W1,
                      float* __restrict__ h, int N) {
    __shared__ float Ws[INC * HID];
    int t = threadIdx.x;
    for (int i = t; i < INC * HID; i += blockDim.x) Ws[i] = W1[i];
    __syncthreads();
    int row = blockIdx.x * 4 + (t >> 6);
    int c = t & 63;
    if (row < N) {
        float acc = 0.f;
        #pragma unroll
        for (int k = 0; k < INC; ++k) acc += x[row * INC + k] * Ws[k * HID + c];
        h[row * HID + c] = acc;
    }
}

// one 64-lane wave per edge; lane = feature
__global__ void k_agg(const int* __restrict__ ei, int E, const float* __restrict__ dis,
                      const float* __restrict__ h, float* __restrict__ out) {
    int lane = threadIdx.x & 63;
    int wave = (blockIdx.x * blockDim.x + threadIdx.x) >> 6;
    int nwaves = (gridDim.x * blockDim.x) >> 6;
    for (int e = wave; e < E; e += nwaves) {
        int src = ei[e];
        int dst = ei[E + e];
        float norm = dis[src] * dis[dst];
        float v = norm * h[src * HID + lane];
        atomicAdd(&out[dst * HID + lane], v);
    }
}

// agg = relu(agg + dis^2*h + b)
__global__ void k_post(float* __restrict__ agg, const float* __restrict__ h,
                       const float* __restrict__ dis, const float* __restrict__ b, int N) {
    int idx = blockIdx.x * blockDim.x + threadIdx.x;
    if (idx < N * HID) {
        int row = idx >> 6, c = idx & 63;
        float d = dis[row];
        float v = agg[idx] + d * d * h[idx] + b[c];
        agg[idx] = v > 0.f ? v : 0.f;
    }
}

// out[N,64] = in[N,64] @ W2[64,64]
__global__ void k_xw2(const float* __restrict__ in, const float* __restrict__ W2,
                      float* __restrict__ outh, int N) {
    __shared__ float Ws[HID * HID];
    int t = threadIdx.x;
    for (int i = t; i < HID * HID; i += blockDim.x) Ws[i] = W2[i];
    __syncthreads();
    int row = blockIdx.x * 4 + (t >> 6);
    int c = t & 63;
    if (row < N) {
        float acc = 0.f;
        const float* r = in + row * HID;
        #pragma unroll
        for (int k = 0; k < HID; ++k) acc += r[k] * Ws[k * HID + c];
        outh[row * HID + c] = acc;
    }
}

// out[i] = dot(h[i,:], Wl) + bl    (wave per row, shfl reduce)
__global__ void k_final(const float* __restrict__ h, const float* __restrict__ Wl,
                        const float* __restrict__ bl, float* __restrict__ out, int N) {
    __shared__ float Wls[HID];
    int t = threadIdx.x;
    if (t < HID) Wls[t] = Wl[t];
    __syncthreads();
    int lane = t & 63;
    int row = (blockIdx.x * blockDim.x + t) >> 6;
    if (row < N) {
        float v = h[row * HID + lane] * Wls[lane];
        #pragma unroll
        for (int off = 32; off > 0; off >>= 1) v += __shfl_down(v, off);
        if (lane == 0) out[row] = v + bl[0];
    }
}

extern "C" void kernel_launch(void* const* d_in, const int* in_sizes, int n_in,
                              void* d_out, int out_size, void* d_ws, size_t ws_size,
                              hipStream_t stream) {
    const float* x  = (const float*)d_in[0];
    const int*   ei = (const int*)d_in[1];
    const float* W1 = (const float*)d_in[2];
    const float* b1 = (const float*)d_in[3];
    const float* W2 = (const float*)d_in[4];
    const float* b2 = (const float*)d_in[5];
    const float* Wl = (const float*)d_in[6];
    const float* bl = (const float*)d_in[7];
    float* out = (float*)d_out;

    const int N = in_sizes[0] / INC;    // 100000
    const int E = in_sizes[1] / 2;      // 3200000

    char* ws = (char*)d_ws;
    size_t off = 0;
    float* dis  = (float*)(ws + off); off += ((size_t)N * 4 + 255) / 256 * 256;
    float* bufA = (float*)(ws + off); off += (size_t)N * HID * 4;
    float* bufB = (float*)(ws + off); off += (size_t)N * HID * 4;

    const int TPB = 256;
    const int rowBlocks  = (N + 3) / 4;            // 4 rows / block
    const int elemBlocks = (N * HID + TPB - 1) / TPB;
    const int aggBlocks  = 16384;                  // grid-stride over edges, 4 edges/block

    // degree + normalization
    k_init_deg<<<(N + TPB - 1) / TPB, TPB, 0, stream>>>(dis, N);
    k_count_deg<<<2048, TPB, 0, stream>>>(ei + E, E, dis);
    k_dis<<<(N + TPB - 1) / TPB, TPB, 0, stream>>>(dis, N);

    // layer 1
    k_xw1<<<rowBlocks, TPB, 0, stream>>>(x, W1, bufA, N);
    hipMemsetAsync(bufB, 0, (size_t)N * HID * 4, stream);
    k_agg<<<aggBlocks, TPB, 0, stream>>>(ei, E, dis, bufA, bufB);
    k_post<<<elemBlocks, TPB, 0, stream>>>(bufB, bufA, dis, b1, N);

    // layer 2
    k_xw2<<<rowBlocks, TPB, 0, stream>>>(bufB, W2, bufA, N);
    hipMemsetAsync(bufB, 0, (size_t)N * HID * 4, stream);
    k_agg<<<aggBlocks, TPB, 0, stream>>>(ei, E, dis, bufA, bufB);
    k_post<<<elemBlocks, TPB, 0, stream>>>(bufB, bufA, dis, b2, N);

    // head
    k_final<<<(N * HID + TPB - 1) / TPB, TPB, 0, stream>>>(bufB, Wl, bl, out, N);
}

// Round 2
// 906.898 us; speedup vs baseline: 1.8310x; 1.8310x over previous
//
#include <hip/hip_runtime.h>

// GCN 2-layer + head, CSR gather-reduce formulation (no f32 atomics).
//
// out[dst] = dis[dst] * ( sum_{src->dst} dis[src]*h[src] + dis[dst]*h[dst] ) + b
// so with g = dis (.) h (folded into matmul epilogue), aggregation is a plain
// neighbor sum + per-row scale. CSR built once (int atomics only), used twice.

#define HID 64
#define INC 11
#define SCAN_CHUNK 1024

// ---- degree / normalization ----
__global__ void k_count_deg(const int* __restrict__ col, int E, int* __restrict__ deg) {
    int i = blockIdx.x * blockDim.x + threadIdx.x;
    int stride = gridDim.x * blockDim.x;
    for (; i < E; i += stride) atomicAdd(&deg[col[i]], 1);
}

__global__ void k_dis(const int* __restrict__ deg, float* __restrict__ dis, int N) {
    int i = blockIdx.x * blockDim.x + threadIdx.x;
    if (i < N) dis[i] = rsqrtf((float)(deg[i] + 1));   // +1 self-loop
}

// ---- exclusive scan of deg -> rowptr (3-kernel, N=100k) ----
__global__ void k_scan1(const int* __restrict__ deg, int N,
                        int* __restrict__ rowptr, int* __restrict__ blocksums) {
    __shared__ int lds[SCAN_CHUNK];
    __shared__ int tsum[256];
    int b = blockIdx.x, t = threadIdx.x;
    int base = b * SCAN_CHUNK;
    for (int i = t; i < SCAN_CHUNK; i += 256)
        lds[i] = (base + i < N) ? deg[base + i] : 0;
    __syncthreads();
    int a0 = lds[t*4], a1 = lds[t*4+1], a2 = lds[t*4+2], a3 = lds[t*4+3];
    int ts = a0 + a1 + a2 + a3;
    tsum[t] = ts;
    __syncthreads();
    for (int off = 1; off < 256; off <<= 1) {
        int v = (t >= off) ? tsum[t - off] : 0;
        __syncthreads();
        tsum[t] += v;
        __syncthreads();
    }
    int excl = tsum[t] - ts;
    int i0 = base + t*4;
    if (i0     < N) rowptr[i0]     = excl;
    if (i0 + 1 < N) rowptr[i0 + 1] = excl + a0;
    if (i0 + 2 < N) rowptr[i0 + 2] = excl + a0 + a1;
    if (i0 + 3 < N) rowptr[i0 + 3] = excl + a0 + a1 + a2;
    if (t == 255) blocksums[b] = tsum[255];
}

__global__ void k_scan2(int* __restrict__ blocksums, int nb, int* __restrict__ blockoff) {
    __shared__ int s[256];
    int t = threadIdx.x;
    s[t] = (t < nb) ? blocksums[t] : 0;
    __syncthreads();
    int mine = s[t];
    for (int off = 1; off < 256; off <<= 1) {
        int v = (t >= off) ? s[t - off] : 0;
        __syncthreads();
        s[t] += v;
        __syncthreads();
    }
    blockoff[t] = s[t] - mine;   // exclusive
}

__global__ void k_scan3(int* __restrict__ rowptr, int* __restrict__ cursor,
                        const int* __restrict__ blockoff, int N, int E) {
    int i = blockIdx.x * blockDim.x + threadIdx.x;
    if (i < N) {
        int v = rowptr[i] + blockoff[i / SCAN_CHUNK];
        rowptr[i] = v;
        cursor[i] = v;
    } else if (i == N) {
        rowptr[N] = E;
    }
}

// ---- CSR scatter (int atomics on 100k cursors) ----
__global__ void k_scatter(const int* __restrict__ ei, int E,
                          int* __restrict__ cursor, int* __restrict__ csr) {
    int i = blockIdx.x * blockDim.x + threadIdx.x;
    int stride = gridDim.x * blockDim.x;
    for (; i < E; i += stride) {
        int src = ei[i];
        int dst = ei[E + i];
        int pos = atomicAdd(&cursor[dst], 1);
        csr[pos] = src;
    }
}

// ---- g[N,64] = dis[row] * (x[N,11] @ W1[11,64]) ----
__global__ void k_xw1(const float* __restrict__ x, const float* __restrict__ W1,
                      const float* __restrict__ dis, float* __restrict__ g, int N) {
    __shared__ float Ws[INC * HID];
    int t = threadIdx.x;
    for (int i = t; i < INC * HID; i += blockDim.x) Ws[i] = W1[i];
    __syncthreads();
    int row = blockIdx.x * 4 + (t >> 6);
    int c = t & 63;
    if (row < N) {
        float acc = 0.f;
        #pragma unroll
        for (int k = 0; k < INC; ++k) acc += x[row * INC + k] * Ws[k * HID + c];
        g[row * HID + c] = dis[row] * acc;
    }
}

// ---- g2[N,64] = dis[row] * (a[N,64] @ W2[64,64]) ----
__global__ void k_xw2(const float* __restrict__ in, const float* __restrict__ W2,
                      const float* __restrict__ dis, float* __restrict__ g, int N) {
    __shared__ float Ws[HID * HID];
    int t = threadIdx.x;
    for (int i = t; i < HID * HID; i += blockDim.x) Ws[i] = W2[i];
    __syncthreads();
    int row = blockIdx.x * 4 + (t >> 6);
    int c = t & 63;
    if (row < N) {
        float acc = 0.f;
        const float* r = in + row * HID;
        #pragma unroll
        for (int k = 0; k < HID; ++k) acc += r[k] * Ws[k * HID + c];
        g[row * HID + c] = dis[row] * acc;
    }
}

// ---- layer-1 aggregation: a[row] = relu(dis[row]*(g[row] + sum g[src]) + b) ----
__global__ void k_agg1(const int* __restrict__ rowptr, const int* __restrict__ csr,
                       const float* __restrict__ g, const float* __restrict__ dis,
                       const float* __restrict__ b, float* __restrict__ outA, int N) {
    int lane = threadIdx.x & 63;
    int row = (blockIdx.x * blockDim.x + threadIdx.x) >> 6;
    if (row >= N) return;
    int s = rowptr[row], e = rowptr[row + 1];
    float acc = g[row * HID + lane];       // self-loop term
    for (int p = s; p < e; p += 64) {
        int idx = (p + lane < e) ? csr[p + lane] : 0;
        int cnt = min(64, e - p);
        for (int j = 0; j < cnt; ++j) {
            int srcn = __shfl(idx, j);
            acc += g[srcn * HID + lane];
        }
    }
    float v = dis[row] * acc + b[lane];
    outA[row * HID + lane] = v > 0.f ? v : 0.f;
}

// ---- layer-2 aggregation fused with head: out[row] = relu(...)·Wl + bl ----
__global__ void k_agg2_head(const int* __restrict__ rowptr, const int* __restrict__ csr,
                            const float* __restrict__ g, const float* __restrict__ dis,
                            const float* __restrict__ b, const float* __restrict__ Wl,
                            const float* __restrict__ bl, float* __restrict__ out, int N) {
    int lane = threadIdx.x & 63;
    int row = (blockIdx.x * blockDim.x + threadIdx.x) >> 6;
    if (row >= N) return;
    int s = rowptr[row], e = rowptr[row + 1];
    float acc = g[row * HID + lane];
    for (int p = s; p < e; p += 64) {
        int idx = (p + lane < e) ? csr[p + lane] : 0;
        int cnt = min(64, e - p);
        for (int j = 0; j < cnt; ++j) {
            int srcn = __shfl(idx, j);
            acc += g[srcn * HID + lane];
        }
    }
    float v = dis[row] * acc + b[lane];
    v = v > 0.f ? v : 0.f;
    v *= Wl[lane];
    #pragma unroll
    for (int off = 32; off > 0; off >>= 1) v += __shfl_down(v, off);
    if (lane == 0) out[row] = v + bl[0];
}

extern "C" void kernel_launch(void* const* d_in, const int* in_sizes, int n_in,
                              void* d_out, int out_size, void* d_ws, size_t ws_size,
                              hipStream_t stream) {
    const float* x  = (const float*)d_in[0];
    const int*   ei = (const int*)d_in[1];
    const float* W1 = (const float*)d_in[2];
    const float* b1 = (const float*)d_in[3];
    const float* W2 = (const float*)d_in[4];
    const float* b2 = (const float*)d_in[5];
    const float* Wl = (const float*)d_in[6];
    const float* bl = (const float*)d_in[7];
    float* out = (float*)d_out;

    const int N = in_sizes[0] / INC;    // 100000
    const int E = in_sizes[1] / 2;      // 3200000

    char* ws = (char*)d_ws;
    size_t off = 0;
    auto alloc = [&](size_t bytes) { void* p = ws + off; off += (bytes + 255) / 256 * 256; return p; };
    int*   deg_i    = (int*)alloc((size_t)N * 4);
    int*   rowptr   = (int*)alloc((size_t)(N + 1) * 4);
    int*   cursor   = (int*)alloc((size_t)N * 4);
    int*   blocksums= (int*)alloc(256 * 4);
    int*   blockoff = (int*)alloc(256 * 4);
    float* dis      = (float*)alloc((size_t)N * 4);
    int*   csr      = (int*)alloc((size_t)E * 4);
    float* bufG     = (float*)alloc((size_t)N * HID * 4);
    float* bufA     = (float*)alloc((size_t)N * HID * 4);

    const int TPB = 256;
    const int nScanBlocks = (N + SCAN_CHUNK - 1) / SCAN_CHUNK;   // 98
    const int rowBlocks   = (N + 3) / 4;
    const int waveBlocks  = ((size_t)N * 64 + TPB - 1) / TPB;    // wave per row

    // CSR build
    hipMemsetAsync(deg_i, 0, (size_t)N * 4, stream);
    k_count_deg<<<2048, TPB, 0, stream>>>(ei + E, E, deg_i);
    k_dis<<<(N + TPB - 1) / TPB, TPB, 0, stream>>>(deg_i, dis, N);
    k_scan1<<<nScanBlocks, TPB, 0, stream>>>(deg_i, N, rowptr, blocksums);
    k_scan2<<<1, TPB, 0, stream>>>(blocksums, nScanBlocks, blockoff);
    k_scan3<<<(N + 1 + TPB - 1) / TPB, TPB, 0, stream>>>(rowptr, cursor, blockoff, N, E);
    k_scatter<<<2048, TPB, 0, stream>>>(ei, E, cursor, csr);

    // layer 1
    k_xw1<<<rowBlocks, TPB, 0, stream>>>(x, W1, dis, bufG, N);
    k_agg1<<<waveBlocks, TPB, 0, stream>>>(rowptr, csr, bufG, dis, b1, bufA, N);

    // layer 2 (+ fused head)
    k_xw2<<<rowBlocks, TPB, 0, stream>>>(bufA, W2, dis, bufG, N);
    k_agg2_head<<<waveBlocks, TPB, 0, stream>>>(rowptr, csr, bufG, dis, b2, Wl, bl, out, N);
}

// Round 3
// 705.800 us; speedup vs baseline: 2.3527x; 1.2849x over previous
//
#include <hip/hip_runtime.h>

// GCN 2-layer + head, CSR gather-reduce formulation (no f32 atomics).
// R3: batched scatter/count (4 atomic chains in flight), unrolled agg gather,
//     persistent-block xw2, dis folded into scan3.

#define HID 64
#define INC 11
#define SCAN_CHUNK 1024

// ---- degree count, int4-batched ----
__global__ void k_count_deg(const int* __restrict__ col, int E, int* __restrict__ deg) {
    int i = blockIdx.x * blockDim.x + threadIdx.x;
    int E4 = E >> 2;
    if (i < E4) {
        int4 d = ((const int4*)col)[i];
        atomicAdd(&deg[d.x], 1);
        atomicAdd(&deg[d.y], 1);
        atomicAdd(&deg[d.z], 1);
        atomicAdd(&deg[d.w], 1);
    }
    // tail
    int r = E & 3;
    if (i < r) atomicAdd(&deg[col[E - r + i]], 1);
}

// ---- exclusive scan of deg -> rowptr ----
__global__ void k_scan1(const int* __restrict__ deg, int N,
                        int* __restrict__ rowptr, int* __restrict__ blocksums) {
    __shared__ int lds[SCAN_CHUNK];
    __shared__ int tsum[256];
    int b = blockIdx.x, t = threadIdx.x;
    int base = b * SCAN_CHUNK;
    for (int i = t; i < SCAN_CHUNK; i += 256)
        lds[i] = (base + i < N) ? deg[base + i] : 0;
    __syncthreads();
    int a0 = lds[t*4], a1 = lds[t*4+1], a2 = lds[t*4+2], a3 = lds[t*4+3];
    int ts = a0 + a1 + a2 + a3;
    tsum[t] = ts;
    __syncthreads();
    for (int off = 1; off < 256; off <<= 1) {
        int v = (t >= off) ? tsum[t - off] : 0;
        __syncthreads();
        tsum[t] += v;
        __syncthreads();
    }
    int excl = tsum[t] - ts;
    int i0 = base + t*4;
    if (i0     < N) rowptr[i0]     = excl;
    if (i0 + 1 < N) rowptr[i0 + 1] = excl + a0;
    if (i0 + 2 < N) rowptr[i0 + 2] = excl + a0 + a1;
    if (i0 + 3 < N) rowptr[i0 + 3] = excl + a0 + a1 + a2;
    if (t == 255) blocksums[b] = tsum[255];
}

__global__ void k_scan2(int* __restrict__ blocksums, int nb, int* __restrict__ blockoff) {
    __shared__ int s[256];
    int t = threadIdx.x;
    s[t] = (t < nb) ? blocksums[t] : 0;
    __syncthreads();
    int mine = s[t];
    for (int off = 1; off < 256; off <<= 1) {
        int v = (t >= off) ? s[t - off] : 0;
        __syncthreads();
        s[t] += v;
        __syncthreads();
    }
    blockoff[t] = s[t] - mine;   // exclusive
}

// rowptr finalize + cursor copy + dis = rsqrt(deg+1)
__global__ void k_scan3(int* __restrict__ rowptr, int* __restrict__ cursor,
                        const int* __restrict__ blockoff, const int* __restrict__ deg,
                        float* __restrict__ dis, int N, int E) {
    int i = blockIdx.x * blockDim.x + threadIdx.x;
    if (i < N) {
        int v = rowptr[i] + blockoff[i / SCAN_CHUNK];
        rowptr[i] = v;
        cursor[i] = v;
        dis[i] = rsqrtf((float)(deg[i] + 1));
    } else if (i == N) {
        rowptr[N] = E;
    }
}

// ---- CSR scatter, int4-batched: 4 atomic chains in flight per thread ----
__global__ void k_scatter(const int* __restrict__ ei, int E,
                          int* __restrict__ cursor, int* __restrict__ csr) {
    int i = blockIdx.x * blockDim.x + threadIdx.x;
    int E4 = E >> 2;
    if (i < E4) {
        int4 s = ((const int4*)ei)[i];
        int4 d = ((const int4*)(ei + E))[i];
        int p0 = atomicAdd(&cursor[d.x], 1);
        int p1 = atomicAdd(&cursor[d.y], 1);
        int p2 = atomicAdd(&cursor[d.z], 1);
        int p3 = atomicAdd(&cursor[d.w], 1);
        csr[p0] = s.x;
        csr[p1] = s.y;
        csr[p2] = s.z;
        csr[p3] = s.w;
    }
    int r = E & 3;
    if (i < r) {
        int e = E - r + i;
        int pos = atomicAdd(&cursor[ei[E + e]], 1);
        csr[pos] = ei[e];
    }
}

// ---- g[N,64] = dis[row] * (x[N,11] @ W1[11,64]) ----
__global__ void k_xw1(const float* __restrict__ x, const float* __restrict__ W1,
                      const float* __restrict__ dis, float* __restrict__ g, int N) {
    __shared__ float Ws[INC * HID];
    int t = threadIdx.x;
    for (int i = t; i < INC * HID; i += blockDim.x) Ws[i] = W1[i];
    __syncthreads();
    int c = t & 63;
    for (int row = blockIdx.x * 4 + (t >> 6); row < N; row += gridDim.x * 4) {
        float acc = 0.f;
        #pragma unroll
        for (int k = 0; k < INC; ++k) acc += x[row * INC + k] * Ws[k * HID + c];
        g[row * HID + c] = dis[row] * acc;
    }
}

// ---- g2[N,64] = dis[row] * (a[N,64] @ W2[64,64]), persistent blocks ----
__global__ void k_xw2(const float* __restrict__ in, const float* __restrict__ W2,
                      const float* __restrict__ dis, float* __restrict__ g, int N) {
    __shared__ float Ws[HID * HID];
    int t = threadIdx.x;
    for (int i = t; i < HID * HID; i += blockDim.x) Ws[i] = W2[i];
    __syncthreads();
    int c = t & 63;
    for (int row = blockIdx.x * 4 + (t >> 6); row < N; row += gridDim.x * 4) {
        const float* r = in + row * HID;
        float acc = 0.f;
        #pragma unroll
        for (int k = 0; k < HID; k += 4) {
            float4 rv = *(const float4*)(r + k);
            acc += rv.x * Ws[(k    ) * HID + c];
            acc += rv.y * Ws[(k + 1) * HID + c];
            acc += rv.z * Ws[(k + 2) * HID + c];
            acc += rv.w * Ws[(k + 3) * HID + c];
        }
        g[row * HID + c] = dis[row] * acc;
    }
}

// ---- neighbor-sum core, 4 gathers in flight ----
__device__ __forceinline__ float agg_row(const int* __restrict__ rowptr,
                                         const int* __restrict__ csr,
                                         const float* __restrict__ g,
                                         int row, int lane) {
    int s = rowptr[row], e = rowptr[row + 1];
    float acc = g[row * HID + lane];       // self-loop term (dis folded in g)
    for (int p = s; p < e; p += 64) {
        int idx = (p + lane < e) ? csr[p + lane] : 0;
        int cnt = min(64, e - p);
        int j = 0;
        for (; j + 3 < cnt; j += 4) {
            int s0 = __shfl(idx, j);
            int s1 = __shfl(idx, j + 1);
            int s2 = __shfl(idx, j + 2);
            int s3 = __shfl(idx, j + 3);
            float v0 = g[s0 * HID + lane];
            float v1 = g[s1 * HID + lane];
            float v2 = g[s2 * HID + lane];
            float v3 = g[s3 * HID + lane];
            acc += v0; acc += v1; acc += v2; acc += v3;
        }
        for (; j < cnt; ++j)
            acc += g[__shfl(idx, j) * HID + lane];
    }
    return acc;
}

// ---- layer-1 aggregation: a[row] = relu(dis[row]*sum + b) ----
__global__ void k_agg1(const int* __restrict__ rowptr, const int* __restrict__ csr,
                       const float* __restrict__ g, const float* __restrict__ dis,
                       const float* __restrict__ b, float* __restrict__ outA, int N) {
    int lane = threadIdx.x & 63;
    int row = (blockIdx.x * blockDim.x + threadIdx.x) >> 6;
    if (row >= N) return;
    float acc = agg_row(rowptr, csr, g, row, lane);
    float v = dis[row] * acc + b[lane];
    outA[row * HID + lane] = v > 0.f ? v : 0.f;
}

// ---- layer-2 aggregation fused with head ----
__global__ void k_agg2_head(const int* __restrict__ rowptr, const int* __restrict__ csr,
                            const float* __restrict__ g, const float* __restrict__ dis,
                            const float* __restrict__ b, const float* __restrict__ Wl,
                            const float* __restrict__ bl, float* __restrict__ out, int N) {
    int lane = threadIdx.x & 63;
    int row = (blockIdx.x * blockDim.x + threadIdx.x) >> 6;
    if (row >= N) return;
    float acc = agg_row(rowptr, csr, g, row, lane);
    float v = dis[row] * acc + b[lane];
    v = v > 0.f ? v : 0.f;
    v *= Wl[lane];
    #pragma unroll
    for (int off = 32; off > 0; off >>= 1) v += __shfl_down(v, off);
    if (lane == 0) out[row] = v + bl[0];
}

extern "C" void kernel_launch(void* const* d_in, const int* in_sizes, int n_in,
                              void* d_out, int out_size, void* d_ws, size_t ws_size,
                              hipStream_t stream) {
    const float* x  = (const float*)d_in[0];
    const int*   ei = (const int*)d_in[1];
    const float* W1 = (const float*)d_in[2];
    const float* b1 = (const float*)d_in[3];
    const float* W2 = (const float*)d_in[4];
    const float* b2 = (const float*)d_in[5];
    const float* Wl = (const float*)d_in[6];
    const float* bl = (const float*)d_in[7];
    float* out = (float*)d_out;

    const int N = in_sizes[0] / INC;    // 100000
    const int E = in_sizes[1] / 2;      // 3200000

    char* ws = (char*)d_ws;
    size_t off = 0;
    auto alloc = [&](size_t bytes) { void* p = ws + off; off += (bytes + 255) / 256 * 256; return p; };
    int*   deg_i    = (int*)alloc((size_t)N * 4);
    int*   rowptr   = (int*)alloc((size_t)(N + 1) * 4);
    int*   cursor   = (int*)alloc((size_t)N * 4);
    int*   blocksums= (int*)alloc(256 * 4);
    int*   blockoff = (int*)alloc(256 * 4);
    float* dis      = (float*)alloc((size_t)N * 4);
    int*   csr      = (int*)alloc((size_t)E * 4);
    float* bufG     = (float*)alloc((size_t)N * HID * 4);
    float* bufA     = (float*)alloc((size_t)N * HID * 4);

    const int TPB = 256;
    const int nScanBlocks = (N + SCAN_CHUNK - 1) / SCAN_CHUNK;   // 98
    const int e4Blocks    = ((E >> 2) + TPB - 1) / TPB;
    const int waveBlocks  = ((size_t)N * 64 + TPB - 1) / TPB;    // wave per row

    // CSR build
    hipMemsetAsync(deg_i, 0, (size_t)N * 4, stream);
    k_count_deg<<<e4Blocks, TPB, 0, stream>>>(ei + E, E, deg_i);
    k_scan1<<<nScanBlocks, TPB, 0, stream>>>(deg_i, N, rowptr, blocksums);
    k_scan2<<<1, TPB, 0, stream>>>(blocksums, nScanBlocks, blockoff);
    k_scan3<<<(N + 1 + TPB - 1) / TPB, TPB, 0, stream>>>(rowptr, cursor, blockoff, deg_i, dis, N, E);
    k_scatter<<<e4Blocks, TPB, 0, stream>>>(ei, E, cursor, csr);

    // layer 1
    k_xw1<<<2048, TPB, 0, stream>>>(x, W1, dis, bufG, N);
    k_agg1<<<waveBlocks, TPB, 0, stream>>>(rowptr, csr, bufG, dis, b1, bufA, N);

    // layer 2 (+ fused head)
    k_xw2<<<2048, TPB, 0, stream>>>(bufA, W2, dis, bufG, N);
    k_agg2_head<<<waveBlocks, TPB, 0, stream>>>(rowptr, csr, bufG, dis, b2, Wl, bl, out, N);
}

// Round 4
// 698.851 us; speedup vs baseline: 2.3761x; 1.0099x over previous
//
#include <hip/hip_runtime.h>

// GCN 2-layer + head, CSR gather-reduce formulation.
// R4: cursor/deg atomics padded to one counter per 64B cache line
//     (stride-16 int) to kill same-line atomic serialization.
//     Padded arrays alias bufG/bufA (written only after their last use).

#define HID 64
#define INC 11
#define SCAN_CHUNK 1024
#define PAD 16   // ints per counter slot (64 B line)

// ---- degree count, int4-batched, line-padded counters ----
__global__ void k_count_deg(const int* __restrict__ col, int E, int* __restrict__ deg) {
    int i = blockIdx.x * blockDim.x + threadIdx.x;
    int E4 = E >> 2;
    if (i < E4) {
        int4 d = ((const int4*)col)[i];
        atomicAdd(&deg[d.x * PAD], 1);
        atomicAdd(&deg[d.y * PAD], 1);
        atomicAdd(&deg[d.z * PAD], 1);
        atomicAdd(&deg[d.w * PAD], 1);
    }
    int r = E & 3;
    if (i < r) atomicAdd(&deg[col[E - r + i] * PAD], 1);
}

// ---- exclusive scan of (padded) deg -> rowptr ----
__global__ void k_scan1(const int* __restrict__ deg, int N,
                        int* __restrict__ rowptr, int* __restrict__ blocksums) {
    __shared__ int lds[SCAN_CHUNK];
    __shared__ int tsum[256];
    int b = blockIdx.x, t = threadIdx.x;
    int base = b * SCAN_CHUNK;
    for (int i = t; i < SCAN_CHUNK; i += 256)
        lds[i] = (base + i < N) ? deg[(size_t)(base + i) * PAD] : 0;
    __syncthreads();
    int a0 = lds[t*4], a1 = lds[t*4+1], a2 = lds[t*4+2], a3 = lds[t*4+3];
    int ts = a0 + a1 + a2 + a3;
    tsum[t] = ts;
    __syncthreads();
    for (int off = 1; off < 256; off <<= 1) {
        int v = (t >= off) ? tsum[t - off] : 0;
        __syncthreads();
        tsum[t] += v;
        __syncthreads();
    }
    int excl = tsum[t] - ts;
    int i0 = base + t*4;
    if (i0     < N) rowptr[i0]     = excl;
    if (i0 + 1 < N) rowptr[i0 + 1] = excl + a0;
    if (i0 + 2 < N) rowptr[i0 + 2] = excl + a0 + a1;
    if (i0 + 3 < N) rowptr[i0 + 3] = excl + a0 + a1 + a2;
    if (t == 255) blocksums[b] = tsum[255];
}

__global__ void k_scan2(int* __restrict__ blocksums, int nb, int* __restrict__ blockoff) {
    __shared__ int s[256];
    int t = threadIdx.x;
    s[t] = (t < nb) ? blocksums[t] : 0;
    __syncthreads();
    int mine = s[t];
    for (int off = 1; off < 256; off <<= 1) {
        int v = (t >= off) ? s[t - off] : 0;
        __syncthreads();
        s[t] += v;
        __syncthreads();
    }
    blockoff[t] = s[t] - mine;   // exclusive
}

// rowptr finalize + padded cursor init + dis = rsqrt(deg+1)
__global__ void k_scan3(int* __restrict__ rowptr, int* __restrict__ cursor,
                        const int* __restrict__ blockoff, const int* __restrict__ deg,
                        float* __restrict__ dis, int N, int E) {
    int i = blockIdx.x * blockDim.x + threadIdx.x;
    if (i < N) {
        int v = rowptr[i] + blockoff[i / SCAN_CHUNK];
        rowptr[i] = v;
        cursor[(size_t)i * PAD] = v;
        dis[i] = rsqrtf((float)(deg[(size_t)i * PAD] + 1));
    } else if (i == N) {
        rowptr[N] = E;
    }
}

// ---- CSR scatter, int4-batched, line-padded cursors ----
__global__ void k_scatter(const int* __restrict__ ei, int E,
                          int* __restrict__ cursor, int* __restrict__ csr) {
    int i = blockIdx.x * blockDim.x + threadIdx.x;
    int E4 = E >> 2;
    if (i < E4) {
        int4 s = ((const int4*)ei)[i];
        int4 d = ((const int4*)(ei + E))[i];
        int p0 = atomicAdd(&cursor[d.x * PAD], 1);
        int p1 = atomicAdd(&cursor[d.y * PAD], 1);
        int p2 = atomicAdd(&cursor[d.z * PAD], 1);
        int p3 = atomicAdd(&cursor[d.w * PAD], 1);
        csr[p0] = s.x;
        csr[p1] = s.y;
        csr[p2] = s.z;
        csr[p3] = s.w;
    }
    int r = E & 3;
    if (i < r) {
        int e = E - r + i;
        int pos = atomicAdd(&cursor[ei[E + e] * PAD], 1);
        csr[pos] = ei[e];
    }
}

// ---- g[N,64] = dis[row] * (x[N,11] @ W1[11,64]) ----
__global__ void k_xw1(const float* __restrict__ x, const float* __restrict__ W1,
                      const float* __restrict__ dis, float* __restrict__ g, int N) {
    __shared__ float Ws[INC * HID];
    int t = threadIdx.x;
    for (int i = t; i < INC * HID; i += blockDim.x) Ws[i] = W1[i];
    __syncthreads();
    int c = t & 63;
    for (int row = blockIdx.x * 4 + (t >> 6); row < N; row += gridDim.x * 4) {
        float acc = 0.f;
        #pragma unroll
        for (int k = 0; k < INC; ++k) acc += x[row * INC + k] * Ws[k * HID + c];
        g[row * HID + c] = dis[row] * acc;
    }
}

// ---- g2[N,64] = dis[row] * (a[N,64] @ W2[64,64]), persistent blocks ----
__global__ void k_xw2(const float* __restrict__ in, const float* __restrict__ W2,
                      const float* __restrict__ dis, float* __restrict__ g, int N) {
    __shared__ float Ws[HID * HID];
    int t = threadIdx.x;
    for (int i = t; i < HID * HID; i += blockDim.x) Ws[i] = W2[i];
    __syncthreads();
    int c = t & 63;
    for (int row = blockIdx.x * 4 + (t >> 6); row < N; row += gridDim.x * 4) {
        const float* r = in + row * HID;
        float acc = 0.f;
        #pragma unroll
        for (int k = 0; k < HID; k += 4) {
            float4 rv = *(const float4*)(r + k);
            acc += rv.x * Ws[(k    ) * HID + c];
            acc += rv.y * Ws[(k + 1) * HID + c];
            acc += rv.z * Ws[(k + 2) * HID + c];
            acc += rv.w * Ws[(k + 3) * HID + c];
        }
        g[row * HID + c] = dis[row] * acc;
    }
}

// ---- neighbor-sum core, 4 gathers in flight ----
__device__ __forceinline__ float agg_row(const int* __restrict__ rowptr,
                                         const int* __restrict__ csr,
                                         const float* __restrict__ g,
                                         int row, int lane) {
    int s = rowptr[row], e = rowptr[row + 1];
    float acc = g[row * HID + lane];       // self-loop term (dis folded in g)
    for (int p = s; p < e; p += 64) {
        int idx = (p + lane < e) ? csr[p + lane] : 0;
        int cnt = min(64, e - p);
        int j = 0;
        for (; j + 3 < cnt; j += 4) {
            int s0 = __shfl(idx, j);
            int s1 = __shfl(idx, j + 1);
            int s2 = __shfl(idx, j + 2);
            int s3 = __shfl(idx, j + 3);
            float v0 = g[s0 * HID + lane];
            float v1 = g[s1 * HID + lane];
            float v2 = g[s2 * HID + lane];
            float v3 = g[s3 * HID + lane];
            acc += v0; acc += v1; acc += v2; acc += v3;
        }
        for (; j < cnt; ++j)
            acc += g[__shfl(idx, j) * HID + lane];
    }
    return acc;
}

// ---- layer-1 aggregation: a[row] = relu(dis[row]*sum + b) ----
__global__ void k_agg1(const int* __restrict__ rowptr, const int* __restrict__ csr,
                       const float* __restrict__ g, const float* __restrict__ dis,
                       const float* __restrict__ b, float* __restrict__ outA, int N) {
    int lane = threadIdx.x & 63;
    int row = (blockIdx.x * blockDim.x + threadIdx.x) >> 6;
    if (row >= N) return;
    float acc = agg_row(rowptr, csr, g, row, lane);
    float v = dis[row] * acc + b[lane];
    outA[row * HID + lane] = v > 0.f ? v : 0.f;
}

// ---- layer-2 aggregation fused with head ----
__global__ void k_agg2_head(const int* __restrict__ rowptr, const int* __restrict__ csr,
                            const float* __restrict__ g, const float* __restrict__ dis,
                            const float* __restrict__ b, const float* __restrict__ Wl,
                            const float* __restrict__ bl, float* __restrict__ out, int N) {
    int lane = threadIdx.x & 63;
    int row = (blockIdx.x * blockDim.x + threadIdx.x) >> 6;
    if (row >= N) return;
    float acc = agg_row(rowptr, csr, g, row, lane);
    float v = dis[row] * acc + b[lane];
    v = v > 0.f ? v : 0.f;
    v *= Wl[lane];
    #pragma unroll
    for (int off = 32; off > 0; off >>= 1) v += __shfl_down(v, off);
    if (lane == 0) out[row] = v + bl[0];
}

extern "C" void kernel_launch(void* const* d_in, const int* in_sizes, int n_in,
                              void* d_out, int out_size, void* d_ws, size_t ws_size,
                              hipStream_t stream) {
    const float* x  = (const float*)d_in[0];
    const int*   ei = (const int*)d_in[1];
    const float* W1 = (const float*)d_in[2];
    const float* b1 = (const float*)d_in[3];
    const float* W2 = (const float*)d_in[4];
    const float* b2 = (const float*)d_in[5];
    const float* Wl = (const float*)d_in[6];
    const float* bl = (const float*)d_in[7];
    float* out = (float*)d_out;

    const int N = in_sizes[0] / INC;    // 100000
    const int E = in_sizes[1] / 2;      // 3200000

    char* ws = (char*)d_ws;
    size_t off = 0;
    auto alloc = [&](size_t bytes) { void* p = ws + off; off += (bytes + 255) / 256 * 256; return p; };
    int*   rowptr   = (int*)alloc((size_t)(N + 1) * 4);
    int*   blocksums= (int*)alloc(256 * 4);
    int*   blockoff = (int*)alloc(256 * 4);
    float* dis      = (float*)alloc((size_t)N * 4);
    int*   csr      = (int*)alloc((size_t)E * 4);
    float* bufG     = (float*)alloc((size_t)N * HID * 4);
    float* bufA     = (float*)alloc((size_t)N * HID * 4);
    // padded counter arrays (N*PAD ints = 6.4 MB) alias the big buffers:
    // deg_p's last read (k_scan3) precedes bufG's first write (k_xw1);
    // cursor_p's last use (k_scatter) precedes bufA's first write (k_agg1).
    int* deg_p    = (int*)bufG;
    int* cursor_p = (int*)bufA;

    const int TPB = 256;
    const int nScanBlocks = (N + SCAN_CHUNK - 1) / SCAN_CHUNK;   // 98
    const int e4Blocks    = ((E >> 2) + TPB - 1) / TPB;
    const int waveBlocks  = ((size_t)N * 64 + TPB - 1) / TPB;    // wave per row

    // CSR build
    hipMemsetAsync(deg_p, 0, (size_t)N * PAD * 4, stream);
    k_count_deg<<<e4Blocks, TPB, 0, stream>>>(ei + E, E, deg_p);
    k_scan1<<<nScanBlocks, TPB, 0, stream>>>(deg_p, N, rowptr, blocksums);
    k_scan2<<<1, TPB, 0, stream>>>(blocksums, nScanBlocks, blockoff);
    k_scan3<<<(N + 1 + TPB - 1) / TPB, TPB, 0, stream>>>(rowptr, cursor_p, blockoff, deg_p, dis, N, E);
    k_scatter<<<e4Blocks, TPB, 0, stream>>>(ei, E, cursor_p, csr);

    // layer 1
    k_xw1<<<2048, TPB, 0, stream>>>(x, W1, dis, bufG, N);
    k_agg1<<<waveBlocks, TPB, 0, stream>>>(rowptr, csr, bufG, dis, b1, bufA, N);

    // layer 2 (+ fused head)
    k_xw2<<<2048, TPB, 0, stream>>>(bufA, W2, dis, bufG, N);
    k_agg2_head<<<waveBlocks, TPB, 0, stream>>>(rowptr, csr, bufG, dis, b2, Wl, bl, out, N);
}